// Round 7
// baseline (170.601 us; speedup 1.0000x reference)
//
#include <hip/hip_runtime.h>
#include <hip/hip_bf16.h>
#include <cstdint>

// Problem: single attention head, B=4 T=2048 C=1024 H=128, causal, scale = C^-0.5.
// Inputs fp32: x[B,T,C], Wq/Wk/Wv[C,H], mask[T,T] int32 (tril, ignored).
// Output fp32 [B,T,H].
//
// R7: both MFMA kernels were latency-exposed, not BW/pipe-bound.
//   0) convert_x: x fp32 -> xb bf16 (streamed once)
//   1) transpose_w: Wt[3][H][C] bf16
//   2) proj v4: 32x32/wave, 768 blocks (3/CU), 4-deep register ring pipeline.
//      q is pre-scaled by C^-0.5 (exact power of 2 in bf16).
//   3) attn v3: split-KV-4 + ones-column l + K-prefetch (next tile) and
//      V-issue before softmax (latency covered by softmax VALU).

typedef __bf16 bf16_t;
typedef __bf16 bf16x4 __attribute__((ext_vector_type(4)));
typedef __bf16 bf16x8 __attribute__((ext_vector_type(8)));
typedef float f32x4 __attribute__((ext_vector_type(4)));

#define MFMA16(a, b, c) __builtin_amdgcn_mfma_f32_16x16x32_bf16(a, b, c, 0, 0, 0)

constexpr int T = 2048;
constexpr int C = 1024;
constexpr int H = 128;

__device__ inline bf16x8 load8f(const float* __restrict__ p) {
    float4 a = *(const float4*)p;
    float4 b = *(const float4*)(p + 4);
    bf16x8 r;
    r[0] = (bf16_t)a.x; r[1] = (bf16_t)a.y; r[2] = (bf16_t)a.z; r[3] = (bf16_t)a.w;
    r[4] = (bf16_t)b.x; r[5] = (bf16_t)b.y; r[6] = (bf16_t)b.z; r[7] = (bf16_t)b.w;
    return r;
}

// ---------------------------------------------------------------------------
// Kernel 0: x fp32 -> bf16, streamed. grid 2048, block 256.
__global__ __launch_bounds__(256) void convert_x(const float* __restrict__ x,
                                                 bf16_t* __restrict__ xb, int n8) {
    int i = blockIdx.x * 256 + threadIdx.x;
    const int stride = gridDim.x * 256;
    for (; i < n8; i += stride)
        *(bf16x8*)(xb + (size_t)i * 8) = load8f(x + (size_t)i * 8);
}

// ---------------------------------------------------------------------------
// Kernel 1: W[C][H] fp32 -> Wt[H][C] bf16. grid (C/32, H/32, 3), block (32,8)
__global__ void transpose_w(const float* __restrict__ Wq,
                            const float* __restrict__ Wk,
                            const float* __restrict__ Wv,
                            bf16_t* __restrict__ Wt) {
    __shared__ bf16_t tile[32][34];
    const float* W = blockIdx.z == 0 ? Wq : (blockIdx.z == 1 ? Wk : Wv);
    const int c0 = blockIdx.x * 32, h0 = blockIdx.y * 32;
    const int tx = threadIdx.x, ty = threadIdx.y;
#pragma unroll
    for (int i = 0; i < 4; i++)
        tile[ty + 8 * i][tx] = (bf16_t)W[(size_t)(c0 + ty + 8 * i) * H + h0 + tx];
    __syncthreads();
    bf16_t* Wtz = Wt + (size_t)blockIdx.z * H * C;
#pragma unroll
    for (int i = 0; i < 4; i++)
        Wtz[(size_t)(h0 + ty + 8 * i) * C + c0 + tx] = tile[tx][ty + 8 * i];
}

// ---------------------------------------------------------------------------
// Kernel 2: y = xb @ W, bf16 MFMA. Per z: M=8192 K=1024 N=128.
// Wave = 32x32 (2 A-frags x 2 B-frags, 4 MFMA/kstep). Block = 64x64, 4 waves.
// grid (128, 2, 3) = 768 blocks (3/CU). 4-deep register ring (K fully unrolled).
// z==0 (q) epilogue folds in C^-0.5 = 1/32 (exact in bf16).
__global__ __launch_bounds__(256) void proj_gemm(const bf16_t* __restrict__ xb,
                                                 const bf16_t* __restrict__ Wt,
                                                 bf16_t* __restrict__ qout,
                                                 bf16_t* __restrict__ kout,
                                                 bf16_t* __restrict__ vtout) {
    const int w = threadIdx.x >> 6;
    const int wm = w & 1, wn = w >> 1;
    const int lane = threadIdx.x & 63;
    const int m16 = lane & 15, g = lane >> 4;
    const int z = blockIdx.z;
    const int m0 = blockIdx.x * 64 + wm * 32;
    const int n0 = blockIdx.y * 64 + wn * 32;     // within z's 128 cols

    const bf16_t* a0p = xb + (size_t)(m0 + m16) * C + g * 8;
    const bf16_t* a1p = a0p + (size_t)16 * C;
    const bf16_t* b0p = Wt + (size_t)(z * H + n0 + m16) * C + g * 8;
    const bf16_t* b1p = b0p + (size_t)16 * C;

    f32x4 zero = {0.f, 0.f, 0.f, 0.f};
    f32x4 acc00 = zero, acc01 = zero, acc10 = zero, acc11 = zero;

    bf16x8 pa0[4], pa1[4], pb0[4], pb1[4];
#pragma unroll
    for (int j = 0; j < 4; j++) {
        pa0[j] = *(const bf16x8*)(a0p + j * 32);
        pa1[j] = *(const bf16x8*)(a1p + j * 32);
        pb0[j] = *(const bf16x8*)(b0p + j * 32);
        pb1[j] = *(const bf16x8*)(b1p + j * 32);
    }

#pragma unroll
    for (int j = 0; j < C / 32; j++) {
        const int s = j & 3;
        acc00 = MFMA16(pa0[s], pb0[s], acc00);
        acc01 = MFMA16(pa0[s], pb1[s], acc01);
        acc10 = MFMA16(pa1[s], pb0[s], acc10);
        acc11 = MFMA16(pa1[s], pb1[s], acc11);
        const int kn = (j + 4) * 32;
        if (kn < C) {
            pa0[s] = *(const bf16x8*)(a0p + kn);
            pa1[s] = *(const bf16x8*)(a1p + kn);
            pb0[s] = *(const bf16x8*)(b0p + kn);
            pb1[s] = *(const bf16x8*)(b1p + kn);
        }
    }

    const float sc = (z == 0) ? 0.03125f : 1.0f;  // fold C^-0.5 into q
    f32x4 acc[2][2] = {{acc00 * sc, acc01 * sc}, {acc10 * sc, acc11 * sc}};

    if (z < 2) {
        bf16_t* out = (z == 0) ? qout : kout;
#pragma unroll
        for (int mf = 0; mf < 2; mf++)
#pragma unroll
            for (int nf = 0; nf < 2; nf++)
#pragma unroll
                for (int ri = 0; ri < 4; ri++) {
                    int r = m0 + mf * 16 + g * 4 + ri;
                    out[(size_t)r * H + n0 + nf * 16 + m16] = (bf16_t)acc[mf][nf][ri];
                }
    } else {
#pragma unroll
        for (int mf = 0; mf < 2; mf++) {
            const int t0 = m0 + mf * 16 + g * 4;  // 4 consecutive t, same batch
            const int bidx = t0 >> 11, t = t0 & (T - 1);
#pragma unroll
            for (int nf = 0; nf < 2; nf++) {
                const int h = n0 + nf * 16 + m16;
                bf16x4 v;
#pragma unroll
                for (int ri = 0; ri < 4; ri++) v[ri] = (bf16_t)acc[mf][nf][ri];
                *(bf16x4*)(vtout + ((size_t)bidx * H + h) * T + t) = v;
            }
        }
    }
}

// ---------------------------------------------------------------------------
// Kernel 3: flash attention, causal, 4-way in-block KV split, ones-column l,
// K prefetched one tile ahead, V issued before softmax. q pre-scaled.
// grid (512), block (256).
__global__ __launch_bounds__(256) void attn(const bf16_t* __restrict__ q,
                                            const bf16_t* __restrict__ k,
                                            const bf16_t* __restrict__ vt,
                                            float* __restrict__ out) {
    __shared__ float accw[4][16][128];            // 32 KiB, scaled partial O
    __shared__ __align__(16) bf16_t pbuf[4][16][40];
    __shared__ float mred[4][16], lred[4][16];
    const int w = threadIdx.x >> 6;
    const int lane = threadIdx.x & 63;
    const int m16 = lane & 15, g = lane >> 4;
    const int b = blockIdx.x & 3;
    const int kk = blockIdx.x >> 2;               // 0..127
    const int qt = (kk < 64) ? kk : 191 - kk;     // reverse-pair load balance
    const int q0 = qt * 16;

    const bf16_t* qb = q + (size_t)b * T * H;
    const bf16_t* kb = k + (size_t)b * T * H;
    const bf16_t* vb = vt + (size_t)b * H * T;

    bf16x8 aq[4];
#pragma unroll
    for (int c = 0; c < 4; c++)
        aq[c] = *(const bf16x8*)(qb + (size_t)(q0 + m16) * H + c * 32 + g * 8);

    bf16x8 ones;
#pragma unroll
    for (int j = 0; j < 8; j++) ones[j] = (bf16_t)1.0f;

    f32x4 zero = {0.f, 0.f, 0.f, 0.f};
    f32x4 acc[9];                                 // [8] = row-sum (l) accumulator
#pragma unroll
    for (int ht = 0; ht < 9; ht++) acc[ht] = zero;
    float mst[4];
#pragma unroll
    for (int ri = 0; ri < 4; ri++) mst[ri] = -1e30f;

    const int kv_end = q0 + 16;
    bf16x8 kc[8], kn[8], vc[8];
    int kv0 = w * 32;
    if (kv0 < kv_end) {
#pragma unroll
        for (int t = 0; t < 2; t++)
#pragma unroll
            for (int c = 0; c < 4; c++)
                kc[t * 4 + c] = *(const bf16x8*)(kb + (size_t)(kv0 + t * 16 + m16) * H + c * 32 + g * 8);
    }

    for (; kv0 < kv_end; kv0 += 128) {
        // S = Q K^T from prefetched K
        f32x4 s[2];
        s[0] = zero; s[1] = zero;
#pragma unroll
        for (int t = 0; t < 2; t++)
#pragma unroll
            for (int c = 0; c < 4; c++)
                s[t] = MFMA16(aq[c], kc[t * 4 + c], s[t]);

        // issue V loads for current tile (latency covered by softmax below)
#pragma unroll
        for (int ht = 0; ht < 8; ht++)
            vc[ht] = *(const bf16x8*)(vb + (size_t)(ht * 16 + m16) * T + kv0 + g * 8);

        // issue K loads for next tile
        const int kvn = kv0 + 128;
        if (kvn < kv_end) {
#pragma unroll
            for (int t = 0; t < 2; t++)
#pragma unroll
                for (int c = 0; c < 4; c++)
                    kn[t * 4 + c] = *(const bf16x8*)(kb + (size_t)(kvn + t * 16 + m16) * H + c * 32 + g * 8);
        }

        // online softmax (q pre-scaled by 1/32)
        float p0v[4], p1v[4];
#pragma unroll
        for (int ri = 0; ri < 4; ri++) {
            const int row = q0 + g * 4 + ri;
            float v0 = s[0][ri];
            float v1 = s[1][ri];
            if (kv0 + m16 > row) v0 = -1e30f;
            if (kv0 + 16 + m16 > row) v1 = -1e30f;
            float rm = fmaxf(v0, v1);
#pragma unroll
            for (int off = 1; off < 16; off <<= 1) rm = fmaxf(rm, __shfl_xor(rm, off));
            const float mnew = fmaxf(mst[ri], rm);
            const float alpha = __expf(mst[ri] - mnew);
            mst[ri] = mnew;
            p0v[ri] = __expf(v0 - mnew);
            p1v[ri] = __expf(v1 - mnew);
#pragma unroll
            for (int ht = 0; ht < 9; ht++) acc[ht][ri] *= alpha;
        }

        // P: C/D layout -> per-wave LDS -> A layout
#pragma unroll
        for (int ri = 0; ri < 4; ri++) {
            pbuf[w][g * 4 + ri][m16] = (bf16_t)p0v[ri];
            pbuf[w][g * 4 + ri][16 + m16] = (bf16_t)p1v[ri];
        }
        bf16x8 ap = *(const bf16x8*)(&pbuf[w][m16][g * 8]);

#pragma unroll
        for (int ht = 0; ht < 8; ht++)
            acc[ht] = MFMA16(ap, vc[ht], acc[ht]);
        acc[8] = MFMA16(ap, ones, acc[8]);        // l += row-sum(P)

#pragma unroll
        for (int i = 0; i < 8; i++) kc[i] = kn[i];
    }

    // ---- cross-wave combine ----
    if (m16 == 0) {
#pragma unroll
        for (int ri = 0; ri < 4; ri++) mred[w][g * 4 + ri] = mst[ri];
    }
    __syncthreads();
    float scale[4];
#pragma unroll
    for (int ri = 0; ri < 4; ri++) {
        const int row = g * 4 + ri;
        float mt = fmaxf(fmaxf(mred[0][row], mred[1][row]),
                         fmaxf(mred[2][row], mred[3][row]));
        scale[ri] = __expf(mst[ri] - mt);
    }
    if (m16 == 0) {
#pragma unroll
        for (int ri = 0; ri < 4; ri++) lred[w][g * 4 + ri] = acc[8][ri] * scale[ri];
    }
#pragma unroll
    for (int ht = 0; ht < 8; ht++)
#pragma unroll
        for (int ri = 0; ri < 4; ri++)
            accw[w][g * 4 + ri][ht * 16 + m16] = acc[ht][ri] * scale[ri];
    __syncthreads();

    float* ob = out + ((size_t)b * T + q0) * H;
    for (int e = threadIdx.x; e < 16 * 128; e += 256) {
        const int row = e >> 7, col = e & 127;
        float o = accw[0][row][col] + accw[1][row][col] +
                  accw[2][row][col] + accw[3][row][col];
        float l = lred[0][row] + lred[1][row] + lred[2][row] + lred[3][row];
        ob[(size_t)row * H + col] = o / l;
    }
}

// ---------------------------------------------------------------------------
extern "C" void kernel_launch(void* const* d_in, const int* in_sizes, int n_in,
                              void* d_out, int out_size, void* d_ws, size_t ws_size,
                              hipStream_t stream) {
    const float* x = (const float*)d_in[0];
    const float* Wq = (const float*)d_in[1];
    const float* Wk = (const float*)d_in[2];
    const float* Wv = (const float*)d_in[3];
    float* out = (float*)d_out;

    char* ws = (char*)d_ws;
    bf16_t* xb = (bf16_t*)ws;                     // 16 MiB
    bf16_t* Wt = (bf16_t*)(ws + 16777216);        // 768 KiB
    char* p = ws + 16777216 + 786432;
    bf16_t* qb = (bf16_t*)(p);                    // 2 MiB each
    bf16_t* kb = (bf16_t*)(p + 2097152);
    bf16_t* vt = (bf16_t*)(p + 2 * 2097152);      // Vt[B][H][T]

    hipLaunchKernelGGL(convert_x, dim3(2048), dim3(256), 0, stream,
                       x, xb, (int)((size_t)4 * T * C / 8));
    hipLaunchKernelGGL(transpose_w, dim3(C / 32, H / 32, 3), dim3(32, 8), 0, stream,
                       Wq, Wk, Wv, Wt);
    hipLaunchKernelGGL(proj_gemm, dim3(128, 2, 3), dim3(256), 0, stream,
                       xb, Wt, qb, kb, vt);
    hipLaunchKernelGGL(attn, dim3(512), dim3(256), 0, stream,
                       qb, kb, vt, out);
}

// Round 8
// 140.670 us; speedup vs baseline: 1.2128x; 1.2128x over previous
//
#include <hip/hip_runtime.h>
#include <hip/hip_bf16.h>
#include <cstdint>

// Problem: single attention head, B=4 T=2048 C=1024 H=128, causal, scale = C^-0.5.
// Inputs fp32: x[B,T,C], Wq/Wk/Wv[C,H], mask[T,T] int32 (tril, ignored).
// Output fp32 [B,T,H].
//
// R8: proj was MLP-bound (~1 load in flight/wave; compiler collapsed the
// register ring to VGPR=32). Fix = m97-style global_load_lds double-buffered
// LDS staging (vmcnt-tracked, VGPR-free MLP) + xor bank swizzle.
//   0) prep: convert x->bf16  +  transpose W->Wt[3][H][C]   (fused, 1 launch)
//   1) proj v5: 64Mx128N/block, BK=64, LDS dbuf via global_load_lds(16B)
//   2) attn: unchanged from R7 (passed; split-KV-4, ones-column l, prefetch)

typedef __bf16 bf16_t;
typedef __bf16 bf16x4 __attribute__((ext_vector_type(4)));
typedef __bf16 bf16x8 __attribute__((ext_vector_type(8)));
typedef float f32x4 __attribute__((ext_vector_type(4)));

#define MFMA16(a, b, c) __builtin_amdgcn_mfma_f32_16x16x32_bf16(a, b, c, 0, 0, 0)

constexpr int T = 2048;
constexpr int C = 1024;
constexpr int H = 128;
constexpr int BK = 64;  // k-chunk (elements)

__device__ inline bf16x8 load8f(const float* __restrict__ p) {
    float4 a = *(const float4*)p;
    float4 b = *(const float4*)(p + 4);
    bf16x8 r;
    r[0] = (bf16_t)a.x; r[1] = (bf16_t)a.y; r[2] = (bf16_t)a.z; r[3] = (bf16_t)a.w;
    r[4] = (bf16_t)b.x; r[5] = (bf16_t)b.y; r[6] = (bf16_t)b.z; r[7] = (bf16_t)b.w;
    return r;
}

// async 16B global -> LDS (wave-uniform LDS base + lane*16; vmcnt-tracked)
__device__ inline void gld16(const bf16_t* g, bf16_t* l) {
    __builtin_amdgcn_global_load_lds(
        (const __attribute__((address_space(1))) unsigned int*)g,
        (__attribute__((address_space(3))) unsigned int*)l, 16, 0, 0);
}

// ---------------------------------------------------------------------------
// Kernel 0: fused prep. Blocks [0,2048): x fp32->bf16. Blocks [2048,2432):
// W[C][H] -> Wt[z][H][C] bf16 (LDS 32x32 transpose). block 256.
__global__ __launch_bounds__(256) void prep(const float* __restrict__ x,
                                            const float* __restrict__ Wq,
                                            const float* __restrict__ Wk,
                                            const float* __restrict__ Wv,
                                            bf16_t* __restrict__ xb,
                                            bf16_t* __restrict__ Wt) {
    const int t = threadIdx.x;
    if (blockIdx.x < 2048) {
        const int n8 = 4 * T * C / 8;             // 1,048,576 groups of 8
        int i = blockIdx.x * 256 + t;
        for (; i < n8; i += 2048 * 256)
            *(bf16x8*)(xb + (size_t)i * 8) = load8f(x + (size_t)i * 8);
    } else {
        __shared__ bf16_t tile[32][34];
        const int b2 = blockIdx.x - 2048;         // 0..383
        const int z = b2 >> 7, rem = b2 & 127;    // z: 0..2
        const int c0 = (rem & 31) * 32, h0 = (rem >> 5) * 32;
        const float* W = z == 0 ? Wq : (z == 1 ? Wk : Wv);
        const int tx = t & 31, ty = t >> 5;
#pragma unroll
        for (int i = 0; i < 4; i++)
            tile[ty + 8 * i][tx] = (bf16_t)W[(size_t)(c0 + ty + 8 * i) * H + h0 + tx];
        __syncthreads();
        bf16_t* Wtz = Wt + (size_t)z * H * C;
#pragma unroll
        for (int i = 0; i < 4; i++)
            Wtz[(size_t)(h0 + ty + 8 * i) * C + c0 + tx] = tile[tx][ty + 8 * i];
    }
}

// ---------------------------------------------------------------------------
// Kernel 1: y = xb @ W, bf16 MFMA, LDS-staged. Per z: M=8192 K=1024 N=128.
// Block: 64M x 128N, 4 waves of 32x64 (wm = w&1, wn = w>>1). BK=64, dbuf.
// Swizzle: logical (row r, 16B-group c8) lives at LDS group v = c8 ^ (r&7).
// Staging is lane-linear in LDS (global_load_lds requirement); the swizzle is
// applied to the GLOBAL source address. grid (128, 3), block 256.
// z==0 (q) epilogue folds in C^-0.5 = 1/32.
__global__ __launch_bounds__(256) void proj_gemm(const bf16_t* __restrict__ xb,
                                                 const bf16_t* __restrict__ Wt,
                                                 bf16_t* __restrict__ qout,
                                                 bf16_t* __restrict__ kout,
                                                 bf16_t* __restrict__ vtout) {
    __shared__ __align__(16) bf16_t Ab[2][64 * BK];    // 8 KiB each
    __shared__ __align__(16) bf16_t Bb[2][128 * BK];   // 16 KiB each
    const int t = threadIdx.x;
    const int w = t >> 6, lane = t & 63;
    const int m16 = lane & 15, g = lane >> 4;
    const int wm = w & 1, wn = w >> 1;
    const int z = blockIdx.y;
    const int m0 = blockIdx.x * 64;
    const bf16_t* Bsrc = Wt + (size_t)z * H * C;

    // ---- staging: A 2 instrs/thread, B 4 instrs/thread, all 16 B ----
    auto stage = [&](int s, int k0) {
#pragma unroll
        for (int i = 0; i < 2; i++) {             // A: e in [0,512)
            const int e = i * 256 + t;
            const int r = e >> 3, v = e & 7, c8 = v ^ (r & 7);
            gld16(xb + (size_t)(m0 + r) * C + k0 + c8 * 8,
                  &Ab[s][(i * 4 + w) * 512]);     // wave-uniform base (w uniform)
        }
#pragma unroll
        for (int i = 0; i < 4; i++) {             // B: e in [0,1024)
            const int e = i * 256 + t;
            const int r = e >> 3, v = e & 7, c8 = v ^ (r & 7);
            gld16(Bsrc + (size_t)r * C + k0 + c8 * 8,
                  &Bb[s][(i * 4 + w) * 512]);
        }
    };

    f32x4 zero = {0.f, 0.f, 0.f, 0.f};
    f32x4 acc[2][4];
#pragma unroll
    for (int mf = 0; mf < 2; mf++)
#pragma unroll
        for (int nf = 0; nf < 4; nf++) acc[mf][nf] = zero;

    stage(0, 0);
    for (int c = 0; c < C / BK; c++) {
        __syncthreads();                          // buf c staged (vmcnt drained)
        if (c + 1 < C / BK) stage((c + 1) & 1, (c + 1) * BK);
        const int s = c & 1;

        bf16x8 af[2][2], bfr[4][2];
#pragma unroll
        for (int mf = 0; mf < 2; mf++)
#pragma unroll
            for (int kf = 0; kf < 2; kf++) {
                const int r = wm * 32 + mf * 16 + m16;
                const int v = (kf * 4 + g) ^ (r & 7);
                af[mf][kf] = *(const bf16x8*)(&Ab[s][r * BK + v * 8]);
            }
#pragma unroll
        for (int nf = 0; nf < 4; nf++)
#pragma unroll
            for (int kf = 0; kf < 2; kf++) {
                const int r = wn * 64 + nf * 16 + m16;
                const int v = (kf * 4 + g) ^ (r & 7);
                bfr[nf][kf] = *(const bf16x8*)(&Bb[s][r * BK + v * 8]);
            }
#pragma unroll
        for (int kf = 0; kf < 2; kf++)
#pragma unroll
            for (int mf = 0; mf < 2; mf++)
#pragma unroll
                for (int nf = 0; nf < 4; nf++)
                    acc[mf][nf] = MFMA16(af[mf][kf], bfr[nf][kf], acc[mf][nf]);
    }

    const float sc = (z == 0) ? 0.03125f : 1.0f;  // fold C^-0.5 into q
    if (z < 2) {
        bf16_t* out = (z == 0) ? qout : kout;
#pragma unroll
        for (int mf = 0; mf < 2; mf++)
#pragma unroll
            for (int nf = 0; nf < 4; nf++)
#pragma unroll
                for (int ri = 0; ri < 4; ri++) {
                    const int r = m0 + wm * 32 + mf * 16 + g * 4 + ri;
                    const int n = wn * 64 + nf * 16 + m16;
                    out[(size_t)r * H + n] = (bf16_t)(acc[mf][nf][ri] * sc);
                }
    } else {
#pragma unroll
        for (int mf = 0; mf < 2; mf++) {
            const int t0 = m0 + wm * 32 + mf * 16 + g * 4;  // 4 consecutive t
            const int bidx = t0 >> 11, tt = t0 & (T - 1);
#pragma unroll
            for (int nf = 0; nf < 4; nf++) {
                const int h = wn * 64 + nf * 16 + m16;
                bf16x4 vv;
#pragma unroll
                for (int ri = 0; ri < 4; ri++) vv[ri] = (bf16_t)acc[mf][nf][ri];
                *(bf16x4*)(vtout + ((size_t)bidx * H + h) * T + tt) = vv;
            }
        }
    }
}

// ---------------------------------------------------------------------------
// Kernel 2: flash attention (unchanged from R7 -- passed). Causal, 4-way
// in-block KV split, ones-column l, K-prefetch, V issued before softmax.
// q pre-scaled by C^-0.5. grid (512), block (256).
__global__ __launch_bounds__(256) void attn(const bf16_t* __restrict__ q,
                                            const bf16_t* __restrict__ k,
                                            const bf16_t* __restrict__ vt,
                                            float* __restrict__ out) {
    __shared__ float accw[4][16][128];
    __shared__ __align__(16) bf16_t pbuf[4][16][40];
    __shared__ float mred[4][16], lred[4][16];
    const int w = threadIdx.x >> 6;
    const int lane = threadIdx.x & 63;
    const int m16 = lane & 15, g = lane >> 4;
    const int b = blockIdx.x & 3;
    const int kk = blockIdx.x >> 2;
    const int qt = (kk < 64) ? kk : 191 - kk;
    const int q0 = qt * 16;

    const bf16_t* qb = q + (size_t)b * T * H;
    const bf16_t* kb = k + (size_t)b * T * H;
    const bf16_t* vb = vt + (size_t)b * H * T;

    bf16x8 aq[4];
#pragma unroll
    for (int c = 0; c < 4; c++)
        aq[c] = *(const bf16x8*)(qb + (size_t)(q0 + m16) * H + c * 32 + g * 8);

    bf16x8 ones;
#pragma unroll
    for (int j = 0; j < 8; j++) ones[j] = (bf16_t)1.0f;

    f32x4 zero = {0.f, 0.f, 0.f, 0.f};
    f32x4 acc[9];
#pragma unroll
    for (int ht = 0; ht < 9; ht++) acc[ht] = zero;
    float mst[4];
#pragma unroll
    for (int ri = 0; ri < 4; ri++) mst[ri] = -1e30f;

    const int kv_end = q0 + 16;
    bf16x8 kc[8], kn[8], vc[8];
    int kv0 = w * 32;
    if (kv0 < kv_end) {
#pragma unroll
        for (int t = 0; t < 2; t++)
#pragma unroll
            for (int c = 0; c < 4; c++)
                kc[t * 4 + c] = *(const bf16x8*)(kb + (size_t)(kv0 + t * 16 + m16) * H + c * 32 + g * 8);
    }

    for (; kv0 < kv_end; kv0 += 128) {
        f32x4 s[2];
        s[0] = zero; s[1] = zero;
#pragma unroll
        for (int t = 0; t < 2; t++)
#pragma unroll
            for (int c = 0; c < 4; c++)
                s[t] = MFMA16(aq[c], kc[t * 4 + c], s[t]);

#pragma unroll
        for (int ht = 0; ht < 8; ht++)
            vc[ht] = *(const bf16x8*)(vb + (size_t)(ht * 16 + m16) * T + kv0 + g * 8);

        const int kvn = kv0 + 128;
        if (kvn < kv_end) {
#pragma unroll
            for (int t = 0; t < 2; t++)
#pragma unroll
                for (int c = 0; c < 4; c++)
                    kn[t * 4 + c] = *(const bf16x8*)(kb + (size_t)(kvn + t * 16 + m16) * H + c * 32 + g * 8);
        }

        float p0v[4], p1v[4];
#pragma unroll
        for (int ri = 0; ri < 4; ri++) {
            const int row = q0 + g * 4 + ri;
            float v0 = s[0][ri];
            float v1 = s[1][ri];
            if (kv0 + m16 > row) v0 = -1e30f;
            if (kv0 + 16 + m16 > row) v1 = -1e30f;
            float rm = fmaxf(v0, v1);
#pragma unroll
            for (int off = 1; off < 16; off <<= 1) rm = fmaxf(rm, __shfl_xor(rm, off));
            const float mnew = fmaxf(mst[ri], rm);
            const float alpha = __expf(mst[ri] - mnew);
            mst[ri] = mnew;
            p0v[ri] = __expf(v0 - mnew);
            p1v[ri] = __expf(v1 - mnew);
#pragma unroll
            for (int ht = 0; ht < 9; ht++) acc[ht][ri] *= alpha;
        }

#pragma unroll
        for (int ri = 0; ri < 4; ri++) {
            pbuf[w][g * 4 + ri][m16] = (bf16_t)p0v[ri];
            pbuf[w][g * 4 + ri][16 + m16] = (bf16_t)p1v[ri];
        }
        bf16x8 ap = *(const bf16x8*)(&pbuf[w][m16][g * 8]);

#pragma unroll
        for (int ht = 0; ht < 8; ht++)
            acc[ht] = MFMA16(ap, vc[ht], acc[ht]);
        acc[8] = MFMA16(ap, ones, acc[8]);

#pragma unroll
        for (int i = 0; i < 8; i++) kc[i] = kn[i];
    }

    if (m16 == 0) {
#pragma unroll
        for (int ri = 0; ri < 4; ri++) mred[w][g * 4 + ri] = mst[ri];
    }
    __syncthreads();
    float scale[4];
#pragma unroll
    for (int ri = 0; ri < 4; ri++) {
        const int row = g * 4 + ri;
        float mt = fmaxf(fmaxf(mred[0][row], mred[1][row]),
                         fmaxf(mred[2][row], mred[3][row]));
        scale[ri] = __expf(mst[ri] - mt);
    }
    if (m16 == 0) {
#pragma unroll
        for (int ri = 0; ri < 4; ri++) lred[w][g * 4 + ri] = acc[8][ri] * scale[ri];
    }
#pragma unroll
    for (int ht = 0; ht < 8; ht++)
#pragma unroll
        for (int ri = 0; ri < 4; ri++)
            accw[w][g * 4 + ri][ht * 16 + m16] = acc[ht][ri] * scale[ri];
    __syncthreads();

    float* ob = out + ((size_t)b * T + q0) * H;
    for (int e = threadIdx.x; e < 16 * 128; e += 256) {
        const int row = e >> 7, col = e & 127;
        float o = accw[0][row][col] + accw[1][row][col] +
                  accw[2][row][col] + accw[3][row][col];
        float l = lred[0][row] + lred[1][row] + lred[2][row] + lred[3][row];
        ob[(size_t)row * H + col] = o / l;
    }
}

// ---------------------------------------------------------------------------
extern "C" void kernel_launch(void* const* d_in, const int* in_sizes, int n_in,
                              void* d_out, int out_size, void* d_ws, size_t ws_size,
                              hipStream_t stream) {
    const float* x = (const float*)d_in[0];
    const float* Wq = (const float*)d_in[1];
    const float* Wk = (const float*)d_in[2];
    const float* Wv = (const float*)d_in[3];
    float* out = (float*)d_out;

    char* ws = (char*)d_ws;
    bf16_t* xb = (bf16_t*)ws;                     // 16 MiB
    bf16_t* Wt = (bf16_t*)(ws + 16777216);        // 768 KiB
    char* p = ws + 16777216 + 786432;
    bf16_t* qb = (bf16_t*)(p);                    // 2 MiB each
    bf16_t* kb = (bf16_t*)(p + 2097152);
    bf16_t* vt = (bf16_t*)(p + 2 * 2097152);      // Vt[B][H][T]

    hipLaunchKernelGGL(prep, dim3(2048 + 384), dim3(256), 0, stream,
                       x, Wq, Wk, Wv, xb, Wt);
    hipLaunchKernelGGL(proj_gemm, dim3(128, 3), dim3(256), 0, stream,
                       xb, Wt, qb, kb, vt);
    hipLaunchKernelGGL(attn, dim3(512), dim3(256), 0, stream,
                       qb, kb, vt, out);
}